// Round 10
// baseline (175.518 us; speedup 1.0000x reference)
//
#include <hip/hip_runtime.h>

// LIF spiking-neuron forward -- DENSE-INSTRUCTION + TASK-PIPELINED version.
// inputs: (B,C,H,W,T) = (8,64,32,32,100) f32, T innermost (stride 1).
// outputs: syn, mem, spike -- each (B,C,H,W,T) f32, concatenated in d_out.
//
// Per pixel, sequential over t:
//   out_t    = (mem - 1 > 0) ? 1 : 0          (uses mem BEFORE update)
//   mem_next = (BETA*mem + syn) * (1 - out)   (uses OLD syn)
//   syn_next = ALPHA*syn + x_t
//
// NUMERICS: f64 recurrence, mul-then-add split by asm value barrier, exact
// double constants -- bit-identical FP sequence to r3-r9 (absmax 2.375,
// threshold 2.74). Only data movement / scheduling changed.
//
// PERF history: r3-r8 plateau 2.2-2.8 TB/s (partial-line global instrs);
// r9 167us / ~5.0 TB/s: EVERY global instr is 1KB lane-contiguous (8 full
// 128B lines -> no ECC RMW), pixel<->time transpose in a wave-private LDS
// slab, zero barriers. r10 attacks the residual 26%: per-task serial head
// (load latency + f64 chain) is exposed because the 26.6KB slab caps
// residency at 6 waves/CU. Fix: persistent waves, 4 tasks each; prefetch
// task i+1's row-block into registers right after task i's deposit (regs
// dead there) -> full load latency hides under task i's recurrence + 6
// store phases. ~240 VGPR peak: harmless at 1-2 waves/SIMD.

typedef float f32x4 __attribute__((ext_vector_type(4)));

constexpr int    T_TOT = 100;
constexpr int    NV4   = 25;     // float4 per pixel row
constexpr int    ROW4  = 26;     // slab row stride in float4 (bank spread)
constexpr int    PPW   = 64;     // pixels per wave-task
constexpr double ALPHA = 0.95;   // exact Python double
constexpr double BETA  = 0.9;    // exact Python double

// round-to-nearest mul then add in f64, contraction-proof.
__device__ __forceinline__ double mul_add_rn64(double a, double b, double c) {
    double p = a * b;
    asm("" : "+v"(p));
    return p + c;
}

// compile-time fence: forbid compiler reordering of LDS ops across phases
// (wave-lockstep + in-order DS pipe make it correct at HW level; zero instrs)
#define WAVE_FENCE()  do { __builtin_amdgcn_wave_barrier(); \
                           asm volatile("" ::: "memory"); } while (0)

// dense store of the slab to one output array: instruction k writes the
// contiguous 1KB [obase + k*1024, +1024) -- 8 full 128B lines, no RMW.
#define STORE_DENSE(OPTR)                                                     \
    do {                                                                      \
        float* ob = (OPTR) + (size_t)pix0 * T_TOT;                            \
        _Pragma("unroll")                                                     \
        for (int k = 0; k < NV4; ++k) {                                       \
            const int g  = 64 * k + lane;                                     \
            const int ps = g / 25;                                            \
            const int es = g - 25 * ps;                                       \
            const f32x4 v = slab[ps * ROW4 + es];                             \
            *reinterpret_cast<f32x4*>(ob + 4 * (size_t)g) = v;                \
        }                                                                     \
    } while (0)

__global__ __launch_bounds__(64)
void lif_fwd(const float* __restrict__ in,
             float* __restrict__ syn_o,
             float* __restrict__ mem_o,
             float* __restrict__ spk_o,
             int ntask)
{
    __shared__ f32x4 slab[PPW * ROW4];     // 26624 B -> 6 waves/CU

    const int lane   = threadIdx.x;        // one wave per block
    const int stride = gridDim.x;

    int task = blockIdx.x;
    if (task >= ntask) return;

    // ---- prefetch first task's row-block (dense 1KB instructions) ----
    f32x4 xb[NV4];
    {
        const float* ib = in + (size_t)task * PPW * T_TOT;
        #pragma unroll
        for (int k = 0; k < NV4; ++k)
            xb[k] = *reinterpret_cast<const f32x4*>(ib + 4 * (size_t)(64 * k + lane));
    }

    for (; task < ntask; task += stride) {
        const int pix0 = task * PPW;

        // ---- deposit xb -> slab (transposed); xb regs die here ----
        #pragma unroll
        for (int k = 0; k < NV4; ++k) {
            const int g  = 64 * k + lane;
            const int ps = g / 25;
            const int es = g - 25 * ps;
            slab[ps * ROW4 + es] = xb[k];
        }
        WAVE_FENCE();

        // ---- issue prefetch of NEXT task now: latency hides under the
        //      recurrence + all six store phases of THIS task (T14) ----
        const int nt = task + stride;
        if (nt < ntask) {
            const float* ib = in + (size_t)nt * PPW * T_TOT;
            #pragma unroll
            for (int k = 0; k < NV4; ++k)
                xb[k] = *reinterpret_cast<const f32x4*>(ib + 4 * (size_t)(64 * k + lane));
        }

        // ---- recurrence (f64, bit-identical r3-r9 path); lane owns pixel ----
        double syn = 0.0, mem = 0.0;
        f32x4 mv[NV4];                         // mem values -> VGPRs
        unsigned smask[4] = {0u, 0u, 0u, 0u};  // spike bits

        #pragma unroll
        for (int e = 0; e < NV4; ++e) {
            const f32x4 xv = slab[lane * ROW4 + e];
            f32x4 sv;
            {
                #pragma clang fp contract(off)
                #pragma unroll
                for (int j = 0; j < 4; ++j) {
                    const int    t     = 4 * e + j;
                    const double x     = (double)xv[j];
                    const bool   o     = (mem - 1.0 > 0.0);
                    const double om    = o ? 0.0 : 1.0;          // == (1 - out)
                    const double mem_n = mul_add_rn64(BETA, mem, syn) * om;
                    const double syn_n = mul_add_rn64(ALPHA, syn, x);
                    sv[j]    = (float)syn_n;
                    mv[e][j] = (float)mem_n;
                    smask[t >> 5] |= (o ? 1u : 0u) << (t & 31);
                    syn = syn_n; mem = mem_n;
                }
            }
            slab[lane * ROW4 + e] = sv;        // in-place: x just consumed
        }
        WAVE_FENCE();

        // ---- syn: dense store ----
        STORE_DENSE(syn_o);
        WAVE_FENCE();

        // ---- mem: refill slab from registers, dense store ----
        #pragma unroll
        for (int e = 0; e < NV4; ++e) slab[lane * ROW4 + e] = mv[e];
        WAVE_FENCE();
        STORE_DENSE(mem_o);
        WAVE_FENCE();

        // ---- spike: expand bitmask, refill, dense store ----
        #pragma unroll
        for (int e = 0; e < NV4; ++e) {
            f32x4 v;
            #pragma unroll
            for (int j = 0; j < 4; ++j) {
                const int t = 4 * e + j;
                v[j] = ((smask[t >> 5] >> (t & 31)) & 1u) ? 1.0f : 0.0f;
            }
            slab[lane * ROW4 + e] = v;
        }
        WAVE_FENCE();
        STORE_DENSE(spk_o);
        WAVE_FENCE();                          // slab reused by next deposit
    }
}

extern "C" void kernel_launch(void* const* d_in, const int* in_sizes, int n_in,
                              void* d_out, int out_size, void* d_ws, size_t ws_size,
                              hipStream_t stream) {
    const float* in = (const float*)d_in[0];
    float* out = (float*)d_out;

    const int n     = in_sizes[0];     // B*C*H*W*T = 52,428,800
    const int npix  = n / T_TOT;       // 524,288
    const int ntask = npix / PPW;      // 8,192

    float* syn_o = out;
    float* mem_o = out + (size_t)n;
    float* spk_o = out + 2 * (size_t)n;

    // 2048 persistent one-wave blocks: 4 tasks each (even), 6 resident/CU
    // by LDS; queued blocks backfill as residents finish.
    dim3 grid(2048);
    dim3 block(64);
    lif_fwd<<<grid, block, 0, stream>>>(in, syn_o, mem_o, spk_o, ntask);
}

// Round 11
// 166.901 us; speedup vs baseline: 1.0516x; 1.0516x over previous
//
#include <hip/hip_runtime.h>

// LIF spiking-neuron forward -- DENSE-INSTRUCTION version (r9, final).
// inputs: (B,C,H,W,T) = (8,64,32,32,100) f32, T innermost (stride 1).
// outputs: syn, mem, spike -- each (B,C,H,W,T) f32, concatenated in d_out.
//
// Per pixel, sequential over t:
//   out_t    = (mem - 1 > 0) ? 1 : 0          (uses mem BEFORE update)
//   mem_next = (BETA*mem + syn) * (1 - out)   (uses OLD syn)
//   syn_next = ALPHA*syn + x_t
//
// NUMERICS: f64 recurrence, mul-then-add split by asm value barrier, exact
// double constants -- bit-identical FP sequence since r3 (absmax 2.375,
// threshold 2.74).
//
// PERF final ledger:
//   r3-r8: 425-580us plateau @ 2.2-2.8 TB/s -- every global instruction
//          touched 16B/80B pieces at 400B stride: partial-line ECC RMW on
//          stores (r6: WRITE 2x ideal) + low in-flight line count. Stream
//          separation (r8) and barrier removal (r5/r7) did not move it.
//   r9:    167us ~ 5.0 TB/s (80% of 6.3 TB/s copy ceiling): EVERY global
//          instruction is 1KB lane-contiguous (8 full 128B lines, no RMW);
//          pixel<->time transpose in a wave-private LDS slab; zero
//          barriers (wave-lockstep + in-order DS pipe).
//   r10:   175us -- explicit cross-task register pipeline REGRESSED
//          (hardware already overlaps the 8192 independent wave-tasks);
//          refuted the serial-head theory -> remaining gap is the memory
//          system's mixed 1R:3W efficiency. ROOFLINE: this is the wall.

typedef float f32x4 __attribute__((ext_vector_type(4)));

constexpr int    T_TOT = 100;
constexpr int    NV4   = 25;     // float4 per pixel row
constexpr int    ROW4  = 26;     // slab row stride in float4 (pad: near-even banks)
constexpr int    PPW   = 64;     // pixels per wave-task
constexpr double ALPHA = 0.95;   // exact Python double
constexpr double BETA  = 0.9;    // exact Python double

// round-to-nearest mul then add in f64, contraction-proof.
__device__ __forceinline__ double mul_add_rn64(double a, double b, double c) {
    double p = a * b;
    asm("" : "+v"(p));
    return p + c;
}

// compile-time fence: forbid compiler reordering of LDS ops across phases
// (wave-lockstep + in-order DS pipe make it correct at HW level; zero instrs)
#define WAVE_FENCE()  do { __builtin_amdgcn_wave_barrier(); \
                           asm volatile("" ::: "memory"); } while (0)

// dense store of the slab to one output array: instruction k writes the
// contiguous 1KB [obase + k*1024, +1024) -- 8 full 128B lines, no RMW.
#define STORE_DENSE(OPTR)                                                     \
    do {                                                                      \
        float* ob = (OPTR) + (size_t)pix0 * T_TOT;                            \
        _Pragma("unroll")                                                     \
        for (int k = 0; k < NV4; ++k) {                                       \
            const int g  = 64 * k + lane;                                     \
            const int ps = g / 25;                                            \
            const int es = g - 25 * ps;                                       \
            const f32x4 v = slab[ps * ROW4 + es];                             \
            *reinterpret_cast<f32x4*>(ob + 4 * (size_t)g) = v;                \
        }                                                                     \
    } while (0)

__global__ __launch_bounds__(64)
void lif_fwd(const float* __restrict__ in,
             float* __restrict__ syn_o,
             float* __restrict__ mem_o,
             float* __restrict__ spk_o)
{
    __shared__ f32x4 slab[PPW * ROW4];     // 26624 B -> 6 waves/CU

    const int lane = threadIdx.x;          // one wave per block
    const int pix0 = blockIdx.x * PPW;
    const float* ib = in + (size_t)pix0 * T_TOT;

    // ---- dense load + transposed deposit into slab ----
    // instr k reads contiguous 1KB; deposit scatters to [pixel][e] slots.
    #pragma unroll
    for (int k = 0; k < NV4; ++k) {
        const int g  = 64 * k + lane;                 // global float4 idx in task
        const f32x4 v = *reinterpret_cast<const f32x4*>(ib + 4 * (size_t)g);
        const int ps = g / 25;
        const int es = g - 25 * ps;
        slab[ps * ROW4 + es] = v;
    }
    WAVE_FENCE();

    // ---- recurrence (f64, bit-identical r3-r9 path); lane owns pixel ----
    // reads x b128 from its slab row, overwrites the slot with syn (f32).
    double syn = 0.0, mem = 0.0;
    f32x4 mv[NV4];                         // mem values, static-indexed -> VGPRs
    unsigned smask[4] = {0u, 0u, 0u, 0u};  // spike bits, static word index

    #pragma unroll
    for (int e = 0; e < NV4; ++e) {
        const f32x4 xv = slab[lane * ROW4 + e];
        f32x4 sv;
        {
            #pragma clang fp contract(off)
            #pragma unroll
            for (int j = 0; j < 4; ++j) {
                const int    t     = 4 * e + j;
                const double x     = (double)xv[j];
                const bool   o     = (mem - 1.0 > 0.0);
                const double om    = o ? 0.0 : 1.0;          // == (1 - out)
                const double mem_n = mul_add_rn64(BETA, mem, syn) * om;
                const double syn_n = mul_add_rn64(ALPHA, syn, x);
                sv[j]    = (float)syn_n;
                mv[e][j] = (float)mem_n;
                smask[t >> 5] |= (o ? 1u : 0u) << (t & 31);
                syn = syn_n; mem = mem_n;
            }
        }
        slab[lane * ROW4 + e] = sv;        // in-place: x just consumed
    }
    WAVE_FENCE();

    // ---- syn: dense store ----
    STORE_DENSE(syn_o);
    WAVE_FENCE();

    // ---- mem: refill slab from registers, dense store ----
    #pragma unroll
    for (int e = 0; e < NV4; ++e) slab[lane * ROW4 + e] = mv[e];
    WAVE_FENCE();
    STORE_DENSE(mem_o);
    WAVE_FENCE();

    // ---- spike: expand bitmask, refill, dense store ----
    #pragma unroll
    for (int e = 0; e < NV4; ++e) {
        f32x4 v;
        #pragma unroll
        for (int j = 0; j < 4; ++j) {
            const int t = 4 * e + j;
            v[j] = ((smask[t >> 5] >> (t & 31)) & 1u) ? 1.0f : 0.0f;
        }
        slab[lane * ROW4 + e] = v;
    }
    WAVE_FENCE();
    STORE_DENSE(spk_o);
}

extern "C" void kernel_launch(void* const* d_in, const int* in_sizes, int n_in,
                              void* d_out, int out_size, void* d_ws, size_t ws_size,
                              hipStream_t stream) {
    const float* in = (const float*)d_in[0];
    float* out = (float*)d_out;

    const int n    = in_sizes[0];      // B*C*H*W*T = 52,428,800
    const int npix = n / T_TOT;        // 524,288

    float* syn_o = out;
    float* mem_o = out + (size_t)n;
    float* spk_o = out + 2 * (size_t)n;

    dim3 grid(npix / PPW);             // 8192 one-wave tasks, no tail
    dim3 block(64);
    lif_fwd<<<grid, block, 0, stream>>>(in, syn_o, mem_o, spk_o);
}